// Round 16
// baseline (963.321 us; speedup 1.0000x reference)
//
#include <hip/hip_runtime.h>
#include <math.h>

#define QN 8
#define CN 1024
#define DN 256
#define NROWS 32768

#define LOSS_OFF 8388608
#define IDX_OFF  8388609

typedef float f32x4v __attribute__((ext_vector_type(4)));
typedef short v8s __attribute__((ext_vector_type(8)));
typedef unsigned short u16;
typedef unsigned short u16x8 __attribute__((ext_vector_type(8)));

__device__ __forceinline__ u16 bfr(float x) {            // f32 -> bf16 RNE (bit ops)
    unsigned u = __float_as_uint(x);
    u += 0x7FFFu + ((u >> 16) & 1u);
    return (u16)(u >> 16);
}
__device__ __forceinline__ float bfs(u16 h) { return __uint_as_float(((unsigned)h) << 16); }

__device__ __forceinline__ void acpB(u16* d, const u16* s) {
    __builtin_amdgcn_global_load_lds(
        (const __attribute__((address_space(1))) unsigned int*)s,
        (__attribute__((address_space(3))) unsigned int*)d, 16, 0, 0);
}

// ---------------------------------------------------------------------------
// Prep: normalize codebooks; store bf16 hi/mid planes AND the exact inv
// (unchanged from round 15 — verified)
// ---------------------------------------------------------------------------
__global__ void rvq_prep(const float* __restrict__ cb,
                         u16* __restrict__ bh, u16* __restrict__ bm,
                         float* __restrict__ invw,
                         float* __restrict__ out) {
    if (blockIdx.x == 0 && threadIdx.x == 0) out[LOSS_OFF] = 0.0f;
    const int wave = threadIdx.x >> 6;
    const int lane = threadIdx.x & 63;
    const int cw = blockIdx.x * 4 + wave;            // q*1024 + c
    float4 v = reinterpret_cast<const float4*>(cb + (size_t)cw * DN)[lane];
    float ss = v.x * v.x + v.y * v.y + v.z * v.z + v.w * v.w;
#pragma unroll
    for (int m = 1; m < 64; m <<= 1) ss += __shfl_xor(ss, m, 64);
    const float inv = 1.0f / fmaxf(sqrtf(ss), 1e-12f);
    if (lane == 0) invw[cw] = inv;
    ushort4 hv, mv;
#define PSPLIT(F, E) { const float x_ = (F) * inv; const u16 h_ = bfr(x_); \
                       hv.E = h_; mv.E = bfr(x_ - bfs(h_)); }
    PSPLIT(v.x, x) PSPLIT(v.y, y) PSPLIT(v.z, z) PSPLIT(v.w, w)
#undef PSPLIT
    reinterpret_cast<ushort4*>(bh + (size_t)cw * DN)[lane] = hv;
    reinterpret_cast<ushort4*>(bm + (size_t)cw * DN)[lane] = mv;
}

// ---------------------------------------------------------------------------
// Main: persistent RVQ, 256 thr / 64 rows per WG, 8 stages.
// Round-16: A-fragments hoisted to registers once per stage (removes 2 of 6
// ds_read_b128 per COMPUTE from the MFMA critical path); top-4 insert screened
// by a single fmaxf. Both transforms bit-identical to round 15's selection.
// ---------------------------------------------------------------------------
__global__ __attribute__((amdgpu_flat_work_group_size(256, 256), amdgpu_waves_per_eu(2, 2)))
void rvq_main(const float* __restrict__ in,
              const float* __restrict__ cb,
              const u16* __restrict__ bh, const u16* __restrict__ bm,
              const float* __restrict__ invw,
              float* __restrict__ out) {
    __shared__ __align__(16) char lds[81920];
    u16* Ah = (u16*)lds;                        // [32 kb][64 row][8]  32 KB
    u16* Am = (u16*)(lds + 32768);              // 32 KB
    u16* Bt = (u16*)(lds + 65536);              // dbuf B tiles, 16 KB
    float* Rres = (float*)lds;                  // alias of Ah/Am: R[k][row] during rerank
    int*   cand = (int*)(lds + 65536);          // alias (64 rows x 4 cands = 1 KB)
    int*   sIdx = (int*)(lds + 65536 + 1024);   // 64 ints
    float* red  = (float*)(lds + 65536 + 1024 + 256);

    const int t   = threadIdx.x;
    const int l   = t & 63;
    const int w   = t >> 6;
    const int g   = l >> 4;
    const int li  = l & 15;
    const int row = l;                          // elementwise row
    const int KS  = w * 64;                     // elementwise k-slice base
    const int w8  = w * 8;
    const int w16 = w * 16;
    const int w16li = w16 + li;
    const int base  = blockIdx.x * 64;

    // residual := inputs, in registers (16 float4 per thread, k = KS + i*4)
    const float* inr0 = in + (size_t)(base + row) * DN + KS;
#define DECLR(i) float4 rr##i = *reinterpret_cast<const float4*>(inr0 + (i) * 4);
    DECLR(0) DECLR(1) DECLR(2) DECLR(3) DECLR(4) DECLR(5) DECLR(6) DECLR(7)
    DECLR(8) DECLR(9) DECLR(10) DECLR(11) DECLR(12) DECLR(13) DECLR(14) DECLR(15)
#undef DECLR
    float lossAcc = 0.0f;

    for (int qs = 0; qs < QN; ++qs) {
        const u16* bhq = bh + ((size_t)qs << 18);
        const u16* bmq = bm + ((size_t)qs << 18);

        // --- split residual into Ah/Am (bf16 hi/mid), layout [kb][row][8]
#define SCV(e, x) { const float xv_ = (x); const u16 hb_ = bfr(xv_); \
                    hh_[e] = hb_; mm_[e] = bfr(xv_ - bfs(hb_)); }
#define SPLITP(p, RA, RB) { u16x8 hh_, mm_; \
        SCV(0, RA.x) SCV(1, RA.y) SCV(2, RA.z) SCV(3, RA.w) \
        SCV(4, RB.x) SCV(5, RB.y) SCV(6, RB.z) SCV(7, RB.w) \
        const int ao_ = ((w8 + (p)) * 64 + row) * 8; \
        *(u16x8*)(Ah + ao_) = hh_; *(u16x8*)(Am + ao_) = mm_; }
        SPLITP(0, rr0, rr1)   SPLITP(1, rr2, rr3)   SPLITP(2, rr4, rr5)
        SPLITP(3, rr6, rr7)   SPLITP(4, rr8, rr9)   SPLITP(5, rr10, rr11)
        SPLITP(6, rr12, rr13) SPLITP(7, rr14, rr15)
#undef SPLITP
#undef SCV

#define STAGE(nb, sp_) { \
        _Pragma("unroll") \
        for (int jj_ = 0; jj_ < 2; ++jj_) { \
            const int d_ = jj_ * 256 + t; \
            const int sub_ = d_ >> 8, pl_ = (d_ >> 7) & 1, kb_ = (d_ >> 5) & 3, col_ = d_ & 31; \
            const int s2_ = (sp_) * 2 + sub_; const int cs2_ = s2_ >> 3, ks2_ = s2_ & 7; \
            const u16* gp_ = (pl_ ? bmq : bhq) + (size_t)(cs2_ * 32 + col_) * DN + ks2_ * 32 + kb_ * 8; \
            acpB(Bt + (nb) * 4096 + d_ * 8, gp_); } }

        // per-row top-4 state (descending v1>=v2>=v3>=v4)
#define DECLT(j) float v1_##j = -INFINITY, v2_##j = -INFINITY, \
                       v3_##j = -INFINITY, v4_##j = -INFINITY; \
                 int i1_##j = 0, i2_##j = 0, i3_##j = 0, i4_##j = 0;
        DECLT(0) DECLT(1) DECLT(2) DECLT(3)
#undef DECLT
        f32x4v accA = (f32x4v){0.f, 0.f, 0.f, 0.f};
        f32x4v accB = (f32x4v){0.f, 0.f, 0.f, 0.f};

#define MRG4(j, vv, ci) { const float v_ = (vv); const int c_ = (ci); \
        if (v_ > v4_##j) { \
            if (v_ > v2_##j) { \
                if (v_ > v1_##j) { v4_##j = v3_##j; i4_##j = i3_##j; v3_##j = v2_##j; i3_##j = i2_##j; \
                                   v2_##j = v1_##j; i2_##j = i1_##j; v1_##j = v_; i1_##j = c_; } \
                else             { v4_##j = v3_##j; i4_##j = i3_##j; v3_##j = v2_##j; i3_##j = i2_##j; \
                                   v2_##j = v_; i2_##j = c_; } \
            } else { \
                if (v_ > v3_##j) { v4_##j = v3_##j; i4_##j = i3_##j; v3_##j = v_; i3_##j = c_; } \
                else             { v4_##j = v_; i4_##j = c_; } \
            } } }

        // COMPUTE with literal KS_ token: A from hoisted regs, B from LDS
#define COMPUTE(bb, KS_) { \
        const u16* bt_ = Bt + ((bb) * 2 + ((KS_) & 1)) * 2048; \
        const v8s bh0_ = *(const v8s*)(bt_ + g * 256 + li * 8); \
        const v8s bh1_ = *(const v8s*)(bt_ + g * 256 + 128 + li * 8); \
        const v8s bm0_ = *(const v8s*)(bt_ + 1024 + g * 256 + li * 8); \
        const v8s bm1_ = *(const v8s*)(bt_ + 1024 + g * 256 + 128 + li * 8); \
        accA = __builtin_amdgcn_mfma_f32_16x16x32_bf16(aH##KS_, bh0_, accA, 0, 0, 0); \
        accA = __builtin_amdgcn_mfma_f32_16x16x32_bf16(aH##KS_, bm0_, accA, 0, 0, 0); \
        accA = __builtin_amdgcn_mfma_f32_16x16x32_bf16(aM##KS_, bh0_, accA, 0, 0, 0); \
        accA = __builtin_amdgcn_mfma_f32_16x16x32_bf16(aM##KS_, bm0_, accA, 0, 0, 0); \
        accB = __builtin_amdgcn_mfma_f32_16x16x32_bf16(aH##KS_, bh1_, accB, 0, 0, 0); \
        accB = __builtin_amdgcn_mfma_f32_16x16x32_bf16(aH##KS_, bm1_, accB, 0, 0, 0); \
        accB = __builtin_amdgcn_mfma_f32_16x16x32_bf16(aM##KS_, bh1_, accB, 0, 0, 0); \
        accB = __builtin_amdgcn_mfma_f32_16x16x32_bf16(aM##KS_, bm1_, accB, 0, 0, 0); }

        // screened merge: one fmaxf gate; skipped inserts leave state identical
#define MERGE_ROW(j, vA, vB) { \
        if (fmaxf((vA), (vB)) > v4_##j) { MRG4(j, (vA), cb0_) MRG4(j, (vB), cb0_ + 16) } }

        STAGE(0, 0)                                  // prologue: tile 0 -> buf 0
        __syncthreads();                             // Ah/Am written + tile 0 drained

        // hoist A fragments for the whole stage (invariant across super-steps)
#define HST(K) \
        const v8s aH##K = *(const v8s*)(Ah + (((K) * 4 + g) * 64 + w16li) * 8); \
        const v8s aM##K = *(const v8s*)(Am + (((K) * 4 + g) * 64 + w16li) * 8);
        HST(0) HST(1) HST(2) HST(3) HST(4) HST(5) HST(6) HST(7)
#undef HST

        for (int cs = 0; cs < 32; ++cs) {            // 32 cod-spans x 8 k-steps
            { const int sp = cs * 4 + 0; if (sp < 127) STAGE(1, sp + 1)
              COMPUTE(0, 0) COMPUTE(0, 1) __syncthreads(); }
            { const int sp = cs * 4 + 1; if (sp < 127) STAGE(0, sp + 1)
              COMPUTE(1, 2) COMPUTE(1, 3) __syncthreads(); }
            { const int sp = cs * 4 + 2; if (sp < 127) STAGE(1, sp + 1)
              COMPUTE(0, 4) COMPUTE(0, 5) __syncthreads(); }
            { const int sp = cs * 4 + 3; if (sp < 127) STAGE(0, sp + 1)
              COMPUTE(1, 6) COMPUTE(1, 7) __syncthreads(); }
            {
                const int cb0_ = (cs << 5) + li;
                MERGE_ROW(0, accA.x, accB.x) MERGE_ROW(1, accA.y, accB.y)
                MERGE_ROW(2, accA.z, accB.z) MERGE_ROW(3, accA.w, accB.w)
                accA = (f32x4v){0.f, 0.f, 0.f, 0.f};
                accB = (f32x4v){0.f, 0.f, 0.f, 0.f};
            }
        }
#undef MERGE_ROW
#undef COMPUTE
#undef STAGE
#undef MRG4

        // --- global top-4 per row via masked butterfly extraction; write to cand[]
#define EXT1(j, GD) { \
        const float cv_ = (p_ == 0) ? v1_##j : (p_ == 1) ? v2_##j : \
                          (p_ == 2) ? v3_##j : (p_ == 3) ? v4_##j : -INFINITY; \
        const int   ci_ = (p_ == 0) ? i1_##j : (p_ == 1) ? i2_##j : \
                          (p_ == 2) ? i3_##j : i4_##j; \
        float bv_ = cv_; int bi_ = ci_; \
        _Pragma("unroll") \
        for (int m = 1; m < 16; m <<= 1) { \
            const float ov = __shfl_xor(bv_, m, 64); \
            const int   oi = __shfl_xor(bi_, m, 64); \
            if (ov > bv_ || (ov == bv_ && oi < bi_)) { bv_ = ov; bi_ = oi; } } \
        GD = bi_; if (p_ < 4 && ci_ == bi_) ++p_; }

#define EXTW(j) { \
        int p_ = 0; int g0_, g1_, g2_, g3_; \
        EXT1(j, g0_) EXT1(j, g1_) EXT1(j, g2_) EXT1(j, g3_) \
        if (li == 0) { int* cp_ = cand + (w16 + g * 4 + (j)) * 4; \
            cp_[0] = g0_; cp_[1] = g1_; cp_[2] = g2_; cp_[3] = g3_; } }
        EXTW(0) EXTW(1) EXTW(2) EXTW(3)
#undef EXTW
#undef EXT1

        __syncthreads();                 // GEMM done everywhere; cand visible

        // --- dump residual registers to R[k][row] (bitwise rounds-1-11 values)
#define DMP(i) { const int k0_ = (KS + (i) * 4) * 64 + row; \
        Rres[k0_] = rr##i.x; Rres[k0_ + 64] = rr##i.y; \
        Rres[k0_ + 128] = rr##i.z; Rres[k0_ + 192] = rr##i.w; }
        DMP(0) DMP(1) DMP(2) DMP(3) DMP(4) DMP(5) DMP(6) DMP(7)
        DMP(8) DMP(9) DMP(10) DMP(11) DMP(12) DMP(13) DMP(14) DMP(15)
#undef DMP
        __syncthreads();                 // R + cand ready for chains

        // --- exact rerank: thread (row = t>>2, cd = t&3) replays the
        //     rounds-1-11 sequential sim chain for its candidate.
        {
            const int crow = t >> 2;
            const int c    = cand[(crow << 2) | (t & 3)];
            const float invc = invw[(qs << 10) + c];
            const float* cr = cb + ((size_t)qs << 18) + (size_t)c * DN;
            float acc = 0.0f;
#pragma unroll 8
            for (int kb = 0; kb < 64; ++kb) {
                const float4 cv = *reinterpret_cast<const float4*>(cr + kb * 4);
                const int k0 = kb * 256 + crow;          // (kb*4)*64 + crow
                acc = fmaf(Rres[k0 +   0], cv.x * invc, acc);
                acc = fmaf(Rres[k0 +  64], cv.y * invc, acc);
                acc = fmaf(Rres[k0 + 128], cv.z * invc, acc);
                acc = fmaf(Rres[k0 + 192], cv.w * invc, acc);
            }
            float sv = acc; int si = c;
#pragma unroll
            for (int m = 1; m < 4; m <<= 1) {
                const float ov = __shfl_xor(sv, m, 64);
                const int   oi = __shfl_xor(si, m, 64);
                if (ov > sv || (ov == sv && oi < si)) { sv = ov; si = oi; }
            }
            if ((t & 3) == 0) sIdx[crow] = si;
        }
        __syncthreads();
        if (t < 64) out[(size_t)IDX_OFF + (size_t)qs * NROWS + base + t] = (float)sIdx[t];

        // --- residual update + loss (registers; raw cb row)
        {
            const int gi = sIdx[row];
            const float* qr = cb + ((size_t)qs << 18) + (size_t)gi * DN + KS;
#define UPD(i) { const float4 qv = *reinterpret_cast<const float4*>(qr + (i) * 4); \
                 rr##i.x -= qv.x; rr##i.y -= qv.y; rr##i.z -= qv.z; rr##i.w -= qv.w; \
                 lossAcc += rr##i.x * rr##i.x + rr##i.y * rr##i.y \
                          + rr##i.z * rr##i.z + rr##i.w * rr##i.w; }
            UPD(0) UPD(1) UPD(2) UPD(3) UPD(4) UPD(5) UPD(6) UPD(7)
            UPD(8) UPD(9) UPD(10) UPD(11) UPD(12) UPD(13) UPD(14) UPD(15)
#undef UPD
        }
        __syncthreads();                 // R/sIdx reads done before next stage writes
    }

    // --- loss: wave butterfly + cross-wave + one atomic per WG
#pragma unroll
    for (int m = 1; m < 64; m <<= 1) lossAcc += __shfl_xor(lossAcc, m, 64);
    if (l == 0) red[w] = lossAcc;
    __syncthreads();
    if (t == 0) {
        const float tot = red[0] + red[1] + red[2] + red[3];
        atomicAdd(out + LOSS_OFF, tot * (1.25f / (8.0f * 8388608.0f)));
    }

    // --- quantized_sum = in - residual: transpose via LDS for coalesced writes
    float* Rf = (float*)lds;
    __syncthreads();
#define TW(i) *reinterpret_cast<float4*>(Rf + row * DN + KS + (i) * 4) = rr##i;
    TW(0) TW(1) TW(2) TW(3) TW(4) TW(5) TW(6) TW(7)
    TW(8) TW(9) TW(10) TW(11) TW(12) TW(13) TW(14) TW(15)
#undef TW
    __syncthreads();
    {
        const int row2 = t >> 2;
        const int kb2  = (t & 3) * 64;
        const float* ir = in + (size_t)(base + row2) * DN + kb2;
        float* orp = out + (size_t)(base + row2) * DN + kb2;
        const float* rf = Rf + row2 * DN + kb2;
#pragma unroll
        for (int i = 0; i < 16; ++i) {
            const float4 rv = *reinterpret_cast<const float4*>(rf + i * 4);
            const float4 iv = *reinterpret_cast<const float4*>(ir + i * 4);
            float4 ov;
            ov.x = iv.x - rv.x; ov.y = iv.y - rv.y;
            ov.z = iv.z - rv.z; ov.w = iv.w - rv.w;
            *reinterpret_cast<float4*>(orp + i * 4) = ov;
        }
    }
}

extern "C" void kernel_launch(void* const* d_in, const int* in_sizes, int n_in,
                              void* d_out, int out_size, void* d_ws, size_t ws_size,
                              hipStream_t stream) {
    (void)in_sizes; (void)n_in; (void)out_size; (void)ws_size;
    const float* in = (const float*)d_in[0];
    const float* cb = (const float*)d_in[1];
    float* out = (float*)d_out;
    u16* bhp = (u16*)d_ws;                          // 4.19 MB hi plane
    u16* bmp = bhp + (size_t)QN * CN * DN;          // 4.19 MB mid plane
    float* invw = (float*)(bmp + (size_t)QN * CN * DN);  // 32 KB inv table

    rvq_prep<<<dim3(2048), dim3(256), 0, stream>>>(cb, bhp, bmp, invw, out);
    rvq_main<<<dim3(512), dim3(256), 0, stream>>>(in, cb, bhp, bmp, invw, out);
}

// Round 17
// 885.763 us; speedup vs baseline: 1.0876x; 1.0876x over previous
//
#include <hip/hip_runtime.h>
#include <math.h>

#define QN 8
#define CN 1024
#define DN 256
#define NROWS 32768

#define LOSS_OFF 8388608
#define IDX_OFF  8388609

typedef float f32x4v __attribute__((ext_vector_type(4)));
typedef short v8s __attribute__((ext_vector_type(8)));
typedef unsigned short u16;
typedef unsigned short u16x8 __attribute__((ext_vector_type(8)));

__device__ __forceinline__ u16 bfr(float x) {            // f32 -> bf16 RNE (bit ops)
    unsigned u = __float_as_uint(x);
    u += 0x7FFFu + ((u >> 16) & 1u);
    return (u16)(u >> 16);
}
__device__ __forceinline__ float bfs(u16 h) { return __uint_as_float(((unsigned)h) << 16); }

__device__ __forceinline__ void acpB(u16* d, const u16* s) {
    __builtin_amdgcn_global_load_lds(
        (const __attribute__((address_space(1))) unsigned int*)s,
        (__attribute__((address_space(3))) unsigned int*)d, 16, 0, 0);
}

// ---------------------------------------------------------------------------
// Prep: normalize codebooks; bf16 hi/mid planes + exact inv (round-15, verified)
// ---------------------------------------------------------------------------
__global__ void rvq_prep(const float* __restrict__ cb,
                         u16* __restrict__ bh, u16* __restrict__ bm,
                         float* __restrict__ invw,
                         float* __restrict__ out) {
    if (blockIdx.x == 0 && threadIdx.x == 0) out[LOSS_OFF] = 0.0f;
    const int wave = threadIdx.x >> 6;
    const int lane = threadIdx.x & 63;
    const int cw = blockIdx.x * 4 + wave;            // q*1024 + c
    float4 v = reinterpret_cast<const float4*>(cb + (size_t)cw * DN)[lane];
    float ss = v.x * v.x + v.y * v.y + v.z * v.z + v.w * v.w;
#pragma unroll
    for (int m = 1; m < 64; m <<= 1) ss += __shfl_xor(ss, m, 64);
    const float inv = 1.0f / fmaxf(sqrtf(ss), 1e-12f);
    if (lane == 0) invw[cw] = inv;
    ushort4 hv, mv;
#define PSPLIT(F, E) { const float x_ = (F) * inv; const u16 h_ = bfr(x_); \
                       hv.E = h_; mv.E = bfr(x_ - bfs(h_)); }
    PSPLIT(v.x, x) PSPLIT(v.y, y) PSPLIT(v.z, z) PSPLIT(v.w, w)
#undef PSPLIT
    reinterpret_cast<ushort4*>(bh + (size_t)cw * DN)[lane] = hv;
    reinterpret_cast<ushort4*>(bm + (size_t)cw * DN)[lane] = mv;
}

// ---------------------------------------------------------------------------
// Main: persistent RVQ, 256 thr / 64 rows per WG, 8 stages.
// Round-17: counted-vmcnt pipeline (T4). Bt = 4 x 4KB flat-step buffers,
// depth-3: per step { vmcnt(2); s_barrier; sched_barrier; stage(tt+3);
// compute(tt) } — loads stay in flight across barriers, no vmcnt(0) drain in
// the main loop. Data order / math byte-identical to round 15 (passed).
// ---------------------------------------------------------------------------
__global__ __attribute__((amdgpu_flat_work_group_size(256, 256), amdgpu_waves_per_eu(2, 2)))
void rvq_main(const float* __restrict__ in,
              const float* __restrict__ cb,
              const u16* __restrict__ bh, const u16* __restrict__ bm,
              const float* __restrict__ invw,
              float* __restrict__ out) {
    __shared__ __align__(16) char lds[81920];
    u16* Ah = (u16*)lds;                        // [32 kb][64 row][8]  32 KB
    u16* Am = (u16*)(lds + 32768);              // 32 KB
    u16* Bt = (u16*)(lds + 65536);              // 4 x 4KB flat-step buffers
    float* Rres = (float*)lds;                  // alias of Ah/Am during rerank
    int*   cand = (int*)(lds + 65536);          // alias buf0 (1 KB; safe, see text)
    int*   sIdx = (int*)(lds + 65536 + 1024);   // 64 ints (still buf0 bytes)
    float* red  = (float*)(lds + 65536 + 1024 + 256);

    const int t   = threadIdx.x;
    const int l   = t & 63;
    const int w   = t >> 6;
    const int g   = l >> 4;
    const int li  = l & 15;
    const int row = l;                          // elementwise row
    const int KS  = w * 64;                     // elementwise k-slice base
    const int w8  = w * 8;
    const int w16 = w * 16;
    const int w16li = w16 + li;
    const int base  = blockIdx.x * 64;

    // residual := inputs, in registers (16 float4 per thread, k = KS + i*4)
    const float* inr0 = in + (size_t)(base + row) * DN + KS;
#define DECLR(i) float4 rr##i = *reinterpret_cast<const float4*>(inr0 + (i) * 4);
    DECLR(0) DECLR(1) DECLR(2) DECLR(3) DECLR(4) DECLR(5) DECLR(6) DECLR(7)
    DECLR(8) DECLR(9) DECLR(10) DECLR(11) DECLR(12) DECLR(13) DECLR(14) DECLR(15)
#undef DECLR
    float lossAcc = 0.0f;

    for (int qs = 0; qs < QN; ++qs) {
        const u16* bhq = bh + ((size_t)qs << 18);
        const u16* bmq = bm + ((size_t)qs << 18);

        // --- split residual into Ah/Am (bf16 hi/mid), layout [kb][row][8]
#define SCV(e, x) { const float xv_ = (x); const u16 hb_ = bfr(xv_); \
                    hh_[e] = hb_; mm_[e] = bfr(xv_ - bfs(hb_)); }
#define SPLITP(p, RA, RB) { u16x8 hh_, mm_; \
        SCV(0, RA.x) SCV(1, RA.y) SCV(2, RA.z) SCV(3, RA.w) \
        SCV(4, RB.x) SCV(5, RB.y) SCV(6, RB.z) SCV(7, RB.w) \
        const int ao_ = ((w8 + (p)) * 64 + row) * 8; \
        *(u16x8*)(Ah + ao_) = hh_; *(u16x8*)(Am + ao_) = mm_; }
        SPLITP(0, rr0, rr1)   SPLITP(1, rr2, rr3)   SPLITP(2, rr4, rr5)
        SPLITP(3, rr6, rr7)   SPLITP(4, rr8, rr9)   SPLITP(5, rr10, rr11)
        SPLITP(6, rr12, rr13) SPLITP(7, rr14, rr15)
#undef SPLITP
#undef SCV

        // one flat step = 4KB = [2 pl][4 kb][32 col][8]; 1 acp16/thread
#define STAGE4(nb, st_) { \
        const int cs2_ = (st_) >> 3, ks2_ = (st_) & 7; \
        const int pl_ = t >> 7, kb_ = (t >> 5) & 3, col_ = t & 31; \
        const u16* gp_ = (pl_ ? bmq : bhq) + (size_t)(cs2_ * 32 + col_) * DN + ks2_ * 32 + kb_ * 8; \
        acpB(Bt + (nb) * 2048 + t * 8, gp_); }

        // per-row top-4 state (descending v1>=v2>=v3>=v4)
#define DECLT(j) float v1_##j = -INFINITY, v2_##j = -INFINITY, \
                       v3_##j = -INFINITY, v4_##j = -INFINITY; \
                 int i1_##j = 0, i2_##j = 0, i3_##j = 0, i4_##j = 0;
        DECLT(0) DECLT(1) DECLT(2) DECLT(3)
#undef DECLT
        f32x4v accA = (f32x4v){0.f, 0.f, 0.f, 0.f};
        f32x4v accB = (f32x4v){0.f, 0.f, 0.f, 0.f};

#define MRG4(j, vv, ci) { const float v_ = (vv); const int c_ = (ci); \
        if (v_ > v4_##j) { \
            if (v_ > v2_##j) { \
                if (v_ > v1_##j) { v4_##j = v3_##j; i4_##j = i3_##j; v3_##j = v2_##j; i3_##j = i2_##j; \
                                   v2_##j = v1_##j; i2_##j = i1_##j; v1_##j = v_; i1_##j = c_; } \
                else             { v4_##j = v3_##j; i4_##j = i3_##j; v3_##j = v2_##j; i3_##j = i2_##j; \
                                   v2_##j = v_; i2_##j = c_; } \
            } else { \
                if (v_ > v3_##j) { v4_##j = v3_##j; i4_##j = i3_##j; v3_##j = v_; i3_##j = c_; } \
                else             { v4_##j = v_; i4_##j = c_; } \
            } } }

#define COMPUTE4(nb, st_) { \
        const int cs_ = (st_) >> 3, ks_ = (st_) & 7; \
        const int ao_ = ((ks_ * 4 + g) * 64 + w16li) * 8; \
        const v8s ah_ = *(const v8s*)(Ah + ao_); \
        const v8s am_ = *(const v8s*)(Am + ao_); \
        const u16* bt_ = Bt + (nb) * 2048; \
        const v8s bh0_ = *(const v8s*)(bt_ + g * 256 + li * 8); \
        const v8s bh1_ = *(const v8s*)(bt_ + g * 256 + 128 + li * 8); \
        const v8s bm0_ = *(const v8s*)(bt_ + 1024 + g * 256 + li * 8); \
        const v8s bm1_ = *(const v8s*)(bt_ + 1024 + g * 256 + 128 + li * 8); \
        accA = __builtin_amdgcn_mfma_f32_16x16x32_bf16(ah_, bh0_, accA, 0, 0, 0); \
        accA = __builtin_amdgcn_mfma_f32_16x16x32_bf16(ah_, bm0_, accA, 0, 0, 0); \
        accA = __builtin_amdgcn_mfma_f32_16x16x32_bf16(am_, bh0_, accA, 0, 0, 0); \
        accA = __builtin_amdgcn_mfma_f32_16x16x32_bf16(am_, bm0_, accA, 0, 0, 0); \
        accB = __builtin_amdgcn_mfma_f32_16x16x32_bf16(ah_, bh1_, accB, 0, 0, 0); \
        accB = __builtin_amdgcn_mfma_f32_16x16x32_bf16(ah_, bm1_, accB, 0, 0, 0); \
        accB = __builtin_amdgcn_mfma_f32_16x16x32_bf16(am_, bh1_, accB, 0, 0, 0); \
        accB = __builtin_amdgcn_mfma_f32_16x16x32_bf16(am_, bm1_, accB, 0, 0, 0); \
        if (ks_ == 7) { \
            const int cb0_ = cs_ * 32 + li; \
            MRG4(0, accA.x, cb0_) MRG4(1, accA.y, cb0_) MRG4(2, accA.z, cb0_) MRG4(3, accA.w, cb0_) \
            MRG4(0, accB.x, cb0_ + 16) MRG4(1, accB.y, cb0_ + 16) \
            MRG4(2, accB.z, cb0_ + 16) MRG4(3, accB.w, cb0_ + 16) \
            accA = (f32x4v){0.f, 0.f, 0.f, 0.f}; accB = (f32x4v){0.f, 0.f, 0.f, 0.f}; } }

#define WBAR(N) asm volatile("s_waitcnt vmcnt(" #N ")" ::: "memory"); \
                __builtin_amdgcn_s_barrier(); \
                __builtin_amdgcn_sched_barrier(0);

        // prologue: 3 steps in flight; full drain once (also covers Ah/Am writes)
        STAGE4(0, 0) STAGE4(1, 1) STAGE4(2, 2)
        __syncthreads();
        STAGE4(3, 3)
        COMPUTE4(0, 0)
        for (int tt = 1; tt <= 252; ++tt) {      // steady state: never drain to 0
            WBAR(2)
            STAGE4((tt + 3) & 3, tt + 3)
            COMPUTE4(tt & 3, tt)
        }
        WBAR(2) COMPUTE4(1, 253)
        WBAR(1) COMPUTE4(2, 254)
        WBAR(0) COMPUTE4(3, 255)
#undef WBAR
#undef COMPUTE4
#undef STAGE4
#undef MRG4

        // --- global top-4 per row via masked butterfly extraction; write to cand[]
#define EXT1(j, GD) { \
        const float cv_ = (p_ == 0) ? v1_##j : (p_ == 1) ? v2_##j : \
                          (p_ == 2) ? v3_##j : (p_ == 3) ? v4_##j : -INFINITY; \
        const int   ci_ = (p_ == 0) ? i1_##j : (p_ == 1) ? i2_##j : \
                          (p_ == 2) ? i3_##j : i4_##j; \
        float bv_ = cv_; int bi_ = ci_; \
        _Pragma("unroll") \
        for (int m = 1; m < 16; m <<= 1) { \
            const float ov = __shfl_xor(bv_, m, 64); \
            const int   oi = __shfl_xor(bi_, m, 64); \
            if (ov > bv_ || (ov == bv_ && oi < bi_)) { bv_ = ov; bi_ = oi; } } \
        GD = bi_; if (p_ < 4 && ci_ == bi_) ++p_; }

#define EXTW(j) { \
        int p_ = 0; int g0_, g1_, g2_, g3_; \
        EXT1(j, g0_) EXT1(j, g1_) EXT1(j, g2_) EXT1(j, g3_) \
        if (li == 0) { int* cp_ = cand + (w16 + g * 4 + (j)) * 4; \
            cp_[0] = g0_; cp_[1] = g1_; cp_[2] = g2_; cp_[3] = g3_; } }
        EXTW(0) EXTW(1) EXTW(2) EXTW(3)
#undef EXTW
#undef EXT1

        __syncthreads();                 // GEMM reads of Ah/Am done; cand visible

        // --- dump residual registers to R[k][row] (bitwise rounds-1-11 values)
#define DMP(i) { const int k0_ = (KS + (i) * 4) * 64 + row; \
        Rres[k0_] = rr##i.x; Rres[k0_ + 64] = rr##i.y; \
        Rres[k0_ + 128] = rr##i.z; Rres[k0_ + 192] = rr##i.w; }
        DMP(0) DMP(1) DMP(2) DMP(3) DMP(4) DMP(5) DMP(6) DMP(7)
        DMP(8) DMP(9) DMP(10) DMP(11) DMP(12) DMP(13) DMP(14) DMP(15)
#undef DMP
        __syncthreads();                 // R + cand ready for chains

        // --- exact rerank: thread (row = t>>2, cd = t&3) replays the
        //     rounds-1-11 sequential sim chain for its candidate.
        {
            const int crow = t >> 2;
            const int c    = cand[(crow << 2) | (t & 3)];
            const float invc = invw[(qs << 10) + c];
            const float* cr = cb + ((size_t)qs << 18) + (size_t)c * DN;
            float acc = 0.0f;
#pragma unroll 8
            for (int kb = 0; kb < 64; ++kb) {
                const float4 cv = *reinterpret_cast<const float4*>(cr + kb * 4);
                const int k0 = kb * 256 + crow;          // (kb*4)*64 + crow
                acc = fmaf(Rres[k0 +   0], cv.x * invc, acc);
                acc = fmaf(Rres[k0 +  64], cv.y * invc, acc);
                acc = fmaf(Rres[k0 + 128], cv.z * invc, acc);
                acc = fmaf(Rres[k0 + 192], cv.w * invc, acc);
            }
            float sv = acc; int si = c;
#pragma unroll
            for (int m = 1; m < 4; m <<= 1) {
                const float ov = __shfl_xor(sv, m, 64);
                const int   oi = __shfl_xor(si, m, 64);
                if (ov > sv || (ov == sv && oi < si)) { sv = ov; si = oi; }
            }
            if ((t & 3) == 0) sIdx[crow] = si;
        }
        __syncthreads();
        if (t < 64) out[(size_t)IDX_OFF + (size_t)qs * NROWS + base + t] = (float)sIdx[t];

        // --- residual update + loss (registers; raw cb row)
        {
            const int gi = sIdx[row];
            const float* qr = cb + ((size_t)qs << 18) + (size_t)gi * DN + KS;
#define UPD(i) { const float4 qv = *reinterpret_cast<const float4*>(qr + (i) * 4); \
                 rr##i.x -= qv.x; rr##i.y -= qv.y; rr##i.z -= qv.z; rr##i.w -= qv.w; \
                 lossAcc += rr##i.x * rr##i.x + rr##i.y * rr##i.y \
                          + rr##i.z * rr##i.z + rr##i.w * rr##i.w; }
            UPD(0) UPD(1) UPD(2) UPD(3) UPD(4) UPD(5) UPD(6) UPD(7)
            UPD(8) UPD(9) UPD(10) UPD(11) UPD(12) UPD(13) UPD(14) UPD(15)
#undef UPD
        }
        __syncthreads();                 // R/sIdx reads done before next stage writes
    }

    // --- loss: wave butterfly + cross-wave + one atomic per WG
#pragma unroll
    for (int m = 1; m < 64; m <<= 1) lossAcc += __shfl_xor(lossAcc, m, 64);
    if (l == 0) red[w] = lossAcc;
    __syncthreads();
    if (t == 0) {
        const float tot = red[0] + red[1] + red[2] + red[3];
        atomicAdd(out + LOSS_OFF, tot * (1.25f / (8.0f * 8388608.0f)));
    }

    // --- quantized_sum = in - residual: transpose via LDS for coalesced writes
    float* Rf = (float*)lds;
    __syncthreads();
#define TW(i) *reinterpret_cast<float4*>(Rf + row * DN + KS + (i) * 4) = rr##i;
    TW(0) TW(1) TW(2) TW(3) TW(4) TW(5) TW(6) TW(7)
    TW(8) TW(9) TW(10) TW(11) TW(12) TW(13) TW(14) TW(15)
#undef TW
    __syncthreads();
    {
        const int row2 = t >> 2;
        const int kb2  = (t & 3) * 64;
        const float* ir = in + (size_t)(base + row2) * DN + kb2;
        float* orp = out + (size_t)(base + row2) * DN + kb2;
        const float* rf = Rf + row2 * DN + kb2;
#pragma unroll
        for (int i = 0; i < 16; ++i) {
            const float4 rv = *reinterpret_cast<const float4*>(rf + i * 4);
            const float4 iv = *reinterpret_cast<const float4*>(ir + i * 4);
            float4 ov;
            ov.x = iv.x - rv.x; ov.y = iv.y - rv.y;
            ov.z = iv.z - rv.z; ov.w = iv.w - rv.w;
            *reinterpret_cast<float4*>(orp + i * 4) = ov;
        }
    }
}

extern "C" void kernel_launch(void* const* d_in, const int* in_sizes, int n_in,
                              void* d_out, int out_size, void* d_ws, size_t ws_size,
                              hipStream_t stream) {
    (void)in_sizes; (void)n_in; (void)out_size; (void)ws_size;
    const float* in = (const float*)d_in[0];
    const float* cb = (const float*)d_in[1];
    float* out = (float*)d_out;
    u16* bhp = (u16*)d_ws;                          // 4.19 MB hi plane
    u16* bmp = bhp + (size_t)QN * CN * DN;          // 4.19 MB mid plane
    float* invw = (float*)(bmp + (size_t)QN * CN * DN);  // 32 KB inv table

    rvq_prep<<<dim3(2048), dim3(256), 0, stream>>>(cb, bhp, bmp, invw, out);
    rvq_main<<<dim3(512), dim3(256), 0, stream>>>(in, cb, bhp, bmp, invw, out);
}

// Round 18
// 842.184 us; speedup vs baseline: 1.1438x; 1.0517x over previous
//
#include <hip/hip_runtime.h>
#include <math.h>

#define QN 8
#define CN 1024
#define DN 256
#define NROWS 32768

#define LOSS_OFF 8388608
#define IDX_OFF  8388609

typedef float f32x4v __attribute__((ext_vector_type(4)));
typedef short v8s __attribute__((ext_vector_type(8)));
typedef unsigned short u16;
typedef unsigned short u16x8 __attribute__((ext_vector_type(8)));

__device__ __forceinline__ u16 bfr(float x) {            // f32 -> bf16 RNE (bit ops)
    unsigned u = __float_as_uint(x);
    u += 0x7FFFu + ((u >> 16) & 1u);
    return (u16)(u >> 16);
}
__device__ __forceinline__ float bfs(u16 h) { return __uint_as_float(((unsigned)h) << 16); }

__device__ __forceinline__ void acpB(u16* d, const u16* s) {
    __builtin_amdgcn_global_load_lds(
        (const __attribute__((address_space(1))) unsigned int*)s,
        (__attribute__((address_space(3))) unsigned int*)d, 16, 0, 0);
}

// ---------------------------------------------------------------------------
// Prep: normalize codebooks; bf16 hi/mid planes + exact inv (round-15, verified)
// ---------------------------------------------------------------------------
__global__ void rvq_prep(const float* __restrict__ cb,
                         u16* __restrict__ bh, u16* __restrict__ bm,
                         float* __restrict__ invw,
                         float* __restrict__ out) {
    if (blockIdx.x == 0 && threadIdx.x == 0) out[LOSS_OFF] = 0.0f;
    const int wave = threadIdx.x >> 6;
    const int lane = threadIdx.x & 63;
    const int cw = blockIdx.x * 4 + wave;            // q*1024 + c
    float4 v = reinterpret_cast<const float4*>(cb + (size_t)cw * DN)[lane];
    float ss = v.x * v.x + v.y * v.y + v.z * v.z + v.w * v.w;
#pragma unroll
    for (int m = 1; m < 64; m <<= 1) ss += __shfl_xor(ss, m, 64);
    const float inv = 1.0f / fmaxf(sqrtf(ss), 1e-12f);
    if (lane == 0) invw[cw] = inv;
    ushort4 hv, mv;
#define PSPLIT(F, E) { const float x_ = (F) * inv; const u16 h_ = bfr(x_); \
                       hv.E = h_; mv.E = bfr(x_ - bfs(h_)); }
    PSPLIT(v.x, x) PSPLIT(v.y, y) PSPLIT(v.z, z) PSPLIT(v.w, w)
#undef PSPLIT
    reinterpret_cast<ushort4*>(bh + (size_t)cw * DN)[lane] = hv;
    reinterpret_cast<ushort4*>(bm + (size_t)cw * DN)[lane] = mv;
}

// ---------------------------------------------------------------------------
// Main: persistent RVQ, 256 thr / 64 rows per WG, 8 stages.
// Round-18 = round-15 structure (best verified) + 3 surgical edits:
//  (a) mm split-term dropped (6 MFMA/COMPUTE; |mm| ~ 1.5e-5 << top-4 band)
//  (b) fmaxf screen on the top-4 merge (bit-identical state)
//  (c) s_setprio(1) around the MFMA cluster (2 independent WGs/CU regime)
// Candidate generation only; exact rerank (rounds-1-11 replay) decides indices.
// ---------------------------------------------------------------------------
__global__ __attribute__((amdgpu_flat_work_group_size(256, 256), amdgpu_waves_per_eu(2, 2)))
void rvq_main(const float* __restrict__ in,
              const float* __restrict__ cb,
              const u16* __restrict__ bh, const u16* __restrict__ bm,
              const float* __restrict__ invw,
              float* __restrict__ out) {
    __shared__ __align__(16) char lds[81920];
    u16* Ah = (u16*)lds;                        // [32 kb][64 row][8]  32 KB
    u16* Am = (u16*)(lds + 32768);              // 32 KB
    u16* Bt = (u16*)(lds + 65536);              // dbuf B tiles, 16 KB
    float* Rres = (float*)lds;                  // alias of Ah/Am during rerank
    int*   cand = (int*)(lds + 65536);          // alias (64 rows x 4 cands = 1 KB)
    int*   sIdx = (int*)(lds + 65536 + 1024);   // 64 ints
    float* red  = (float*)(lds + 65536 + 1024 + 256);

    const int t   = threadIdx.x;
    const int l   = t & 63;
    const int w   = t >> 6;
    const int g   = l >> 4;
    const int li  = l & 15;
    const int row = l;                          // elementwise row
    const int KS  = w * 64;                     // elementwise k-slice base
    const int w8  = w * 8;
    const int w16 = w * 16;
    const int w16li = w16 + li;
    const int base  = blockIdx.x * 64;

    // residual := inputs, in registers (16 float4 per thread, k = KS + i*4)
    const float* inr0 = in + (size_t)(base + row) * DN + KS;
#define DECLR(i) float4 rr##i = *reinterpret_cast<const float4*>(inr0 + (i) * 4);
    DECLR(0) DECLR(1) DECLR(2) DECLR(3) DECLR(4) DECLR(5) DECLR(6) DECLR(7)
    DECLR(8) DECLR(9) DECLR(10) DECLR(11) DECLR(12) DECLR(13) DECLR(14) DECLR(15)
#undef DECLR
    float lossAcc = 0.0f;

    for (int qs = 0; qs < QN; ++qs) {
        const u16* bhq = bh + ((size_t)qs << 18);
        const u16* bmq = bm + ((size_t)qs << 18);

        // --- split residual into Ah/Am (bf16 hi/mid), layout [kb][row][8]
#define SCV(e, x) { const float xv_ = (x); const u16 hb_ = bfr(xv_); \
                    hh_[e] = hb_; mm_[e] = bfr(xv_ - bfs(hb_)); }
#define SPLITP(p, RA, RB) { u16x8 hh_, mm_; \
        SCV(0, RA.x) SCV(1, RA.y) SCV(2, RA.z) SCV(3, RA.w) \
        SCV(4, RB.x) SCV(5, RB.y) SCV(6, RB.z) SCV(7, RB.w) \
        const int ao_ = ((w8 + (p)) * 64 + row) * 8; \
        *(u16x8*)(Ah + ao_) = hh_; *(u16x8*)(Am + ao_) = mm_; }
        SPLITP(0, rr0, rr1)   SPLITP(1, rr2, rr3)   SPLITP(2, rr4, rr5)
        SPLITP(3, rr6, rr7)   SPLITP(4, rr8, rr9)   SPLITP(5, rr10, rr11)
        SPLITP(6, rr12, rr13) SPLITP(7, rr14, rr15)
#undef SPLITP
#undef SCV

#define STAGE(nb, sp_) { \
        _Pragma("unroll") \
        for (int jj_ = 0; jj_ < 2; ++jj_) { \
            const int d_ = jj_ * 256 + t; \
            const int sub_ = d_ >> 8, pl_ = (d_ >> 7) & 1, kb_ = (d_ >> 5) & 3, col_ = d_ & 31; \
            const int s2_ = (sp_) * 2 + sub_; const int cs2_ = s2_ >> 3, ks2_ = s2_ & 7; \
            const u16* gp_ = (pl_ ? bmq : bhq) + (size_t)(cs2_ * 32 + col_) * DN + ks2_ * 32 + kb_ * 8; \
            acpB(Bt + (nb) * 4096 + d_ * 8, gp_); } }

        // per-row top-4 state (descending v1>=v2>=v3>=v4)
#define DECLT(j) float v1_##j = -INFINITY, v2_##j = -INFINITY, \
                       v3_##j = -INFINITY, v4_##j = -INFINITY; \
                 int i1_##j = 0, i2_##j = 0, i3_##j = 0, i4_##j = 0;
        DECLT(0) DECLT(1) DECLT(2) DECLT(3)
#undef DECLT
        f32x4v accA = (f32x4v){0.f, 0.f, 0.f, 0.f};
        f32x4v accB = (f32x4v){0.f, 0.f, 0.f, 0.f};

#define MRG4(j, vv, ci) { const float v_ = (vv); const int c_ = (ci); \
        if (v_ > v4_##j) { \
            if (v_ > v2_##j) { \
                if (v_ > v1_##j) { v4_##j = v3_##j; i4_##j = i3_##j; v3_##j = v2_##j; i3_##j = i2_##j; \
                                   v2_##j = v1_##j; i2_##j = i1_##j; v1_##j = v_; i1_##j = c_; } \
                else             { v4_##j = v3_##j; i4_##j = i3_##j; v3_##j = v2_##j; i3_##j = i2_##j; \
                                   v2_##j = v_; i2_##j = c_; } \
            } else { \
                if (v_ > v3_##j) { v4_##j = v3_##j; i4_##j = i3_##j; v3_##j = v_; i3_##j = c_; } \
                else             { v4_##j = v_; i4_##j = c_; } \
            } } }

        // screened merge: one fmaxf gate per row; skipped inserts leave state identical
#define MROW(j, vA, vB) { \
        if (fmaxf((vA), (vB)) > v4_##j) { MRG4(j, (vA), cb0_) MRG4(j, (vB), cb0_ + 16) } }

#define COMPUTE(bb, sub) { \
        const int s_ = sp * 2 + (sub); const int cs_ = s_ >> 3, ks_ = s_ & 7; \
        const int ao_ = ((ks_ * 4 + g) * 64 + w16li) * 8; \
        const v8s ah_ = *(const v8s*)(Ah + ao_); \
        const v8s am_ = *(const v8s*)(Am + ao_); \
        const u16* bt_ = Bt + ((bb) * 2 + (sub)) * 2048; \
        const v8s bh0_ = *(const v8s*)(bt_ + g * 256 + li * 8); \
        const v8s bh1_ = *(const v8s*)(bt_ + g * 256 + 128 + li * 8); \
        const v8s bm0_ = *(const v8s*)(bt_ + 1024 + g * 256 + li * 8); \
        const v8s bm1_ = *(const v8s*)(bt_ + 1024 + g * 256 + 128 + li * 8); \
        __builtin_amdgcn_s_setprio(1); \
        accA = __builtin_amdgcn_mfma_f32_16x16x32_bf16(ah_, bh0_, accA, 0, 0, 0); \
        accA = __builtin_amdgcn_mfma_f32_16x16x32_bf16(ah_, bm0_, accA, 0, 0, 0); \
        accA = __builtin_amdgcn_mfma_f32_16x16x32_bf16(am_, bh0_, accA, 0, 0, 0); \
        accB = __builtin_amdgcn_mfma_f32_16x16x32_bf16(ah_, bh1_, accB, 0, 0, 0); \
        accB = __builtin_amdgcn_mfma_f32_16x16x32_bf16(ah_, bm1_, accB, 0, 0, 0); \
        accB = __builtin_amdgcn_mfma_f32_16x16x32_bf16(am_, bh1_, accB, 0, 0, 0); \
        __builtin_amdgcn_s_setprio(0); \
        if (ks_ == 7) { \
            const int cb0_ = cs_ * 32 + li; \
            MROW(0, accA.x, accB.x) MROW(1, accA.y, accB.y) \
            MROW(2, accA.z, accB.z) MROW(3, accA.w, accB.w) \
            accA = (f32x4v){0.f, 0.f, 0.f, 0.f}; accB = (f32x4v){0.f, 0.f, 0.f, 0.f}; } }

        STAGE(0, 0)                                  // prologue (drained at first barrier)
        for (int sp = 0; sp < 128; ++sp) {           // 128 super-steps x 2 flat steps
            __syncthreads();                          // Ah/Am + buf[sp&1] ready
            const int bb = sp & 1;
            if (sp < 127) STAGE(bb ^ 1, sp + 1)
            COMPUTE(bb, 0)
            COMPUTE(bb, 1)
        }
#undef COMPUTE
#undef MROW
#undef STAGE
#undef MRG4

        // --- global top-4 per row via masked butterfly extraction; write to cand[]
#define EXT1(j, GD) { \
        const float cv_ = (p_ == 0) ? v1_##j : (p_ == 1) ? v2_##j : \
                          (p_ == 2) ? v3_##j : (p_ == 3) ? v4_##j : -INFINITY; \
        const int   ci_ = (p_ == 0) ? i1_##j : (p_ == 1) ? i2_##j : \
                          (p_ == 2) ? i3_##j : i4_##j; \
        float bv_ = cv_; int bi_ = ci_; \
        _Pragma("unroll") \
        for (int m = 1; m < 16; m <<= 1) { \
            const float ov = __shfl_xor(bv_, m, 64); \
            const int   oi = __shfl_xor(bi_, m, 64); \
            if (ov > bv_ || (ov == bv_ && oi < bi_)) { bv_ = ov; bi_ = oi; } } \
        GD = bi_; if (p_ < 4 && ci_ == bi_) ++p_; }

#define EXTW(j) { \
        int p_ = 0; int g0_, g1_, g2_, g3_; \
        EXT1(j, g0_) EXT1(j, g1_) EXT1(j, g2_) EXT1(j, g3_) \
        if (li == 0) { int* cp_ = cand + (w16 + g * 4 + (j)) * 4; \
            cp_[0] = g0_; cp_[1] = g1_; cp_[2] = g2_; cp_[3] = g3_; } }
        EXTW(0) EXTW(1) EXTW(2) EXTW(3)
#undef EXTW
#undef EXT1

        __syncthreads();                 // GEMM reads of Ah/Am done; cand visible

        // --- dump residual registers to R[k][row] (bitwise rounds-1-11 values)
#define DMP(i) { const int k0_ = (KS + (i) * 4) * 64 + row; \
        Rres[k0_] = rr##i.x; Rres[k0_ + 64] = rr##i.y; \
        Rres[k0_ + 128] = rr##i.z; Rres[k0_ + 192] = rr##i.w; }
        DMP(0) DMP(1) DMP(2) DMP(3) DMP(4) DMP(5) DMP(6) DMP(7)
        DMP(8) DMP(9) DMP(10) DMP(11) DMP(12) DMP(13) DMP(14) DMP(15)
#undef DMP
        __syncthreads();                 // R + cand ready for chains

        // --- exact rerank: thread (row = t>>2, cd = t&3) replays the
        //     rounds-1-11 sequential sim chain for its candidate.
        {
            const int crow = t >> 2;
            const int c    = cand[(crow << 2) | (t & 3)];
            const float invc = invw[(qs << 10) + c];
            const float* cr = cb + ((size_t)qs << 18) + (size_t)c * DN;
            float acc = 0.0f;
#pragma unroll 8
            for (int kb = 0; kb < 64; ++kb) {
                const float4 cv = *reinterpret_cast<const float4*>(cr + kb * 4);
                const int k0 = kb * 256 + crow;          // (kb*4)*64 + crow
                acc = fmaf(Rres[k0 +   0], cv.x * invc, acc);
                acc = fmaf(Rres[k0 +  64], cv.y * invc, acc);
                acc = fmaf(Rres[k0 + 128], cv.z * invc, acc);
                acc = fmaf(Rres[k0 + 192], cv.w * invc, acc);
            }
            float sv = acc; int si = c;
#pragma unroll
            for (int m = 1; m < 4; m <<= 1) {
                const float ov = __shfl_xor(sv, m, 64);
                const int   oi = __shfl_xor(si, m, 64);
                if (ov > sv || (ov == sv && oi < si)) { sv = ov; si = oi; }
            }
            if ((t & 3) == 0) sIdx[crow] = si;
        }
        __syncthreads();
        if (t < 64) out[(size_t)IDX_OFF + (size_t)qs * NROWS + base + t] = (float)sIdx[t];

        // --- residual update + loss (registers; raw cb row)
        {
            const int gi = sIdx[row];
            const float* qr = cb + ((size_t)qs << 18) + (size_t)gi * DN + KS;
#define UPD(i) { const float4 qv = *reinterpret_cast<const float4*>(qr + (i) * 4); \
                 rr##i.x -= qv.x; rr##i.y -= qv.y; rr##i.z -= qv.z; rr##i.w -= qv.w; \
                 lossAcc += rr##i.x * rr##i.x + rr##i.y * rr##i.y \
                          + rr##i.z * rr##i.z + rr##i.w * rr##i.w; }
            UPD(0) UPD(1) UPD(2) UPD(3) UPD(4) UPD(5) UPD(6) UPD(7)
            UPD(8) UPD(9) UPD(10) UPD(11) UPD(12) UPD(13) UPD(14) UPD(15)
#undef UPD
        }
        __syncthreads();                 // R/sIdx reads done before next stage writes
    }

    // --- loss: wave butterfly + cross-wave + one atomic per WG
#pragma unroll
    for (int m = 1; m < 64; m <<= 1) lossAcc += __shfl_xor(lossAcc, m, 64);
    if (l == 0) red[w] = lossAcc;
    __syncthreads();
    if (t == 0) {
        const float tot = red[0] + red[1] + red[2] + red[3];
        atomicAdd(out + LOSS_OFF, tot * (1.25f / (8.0f * 8388608.0f)));
    }

    // --- quantized_sum = in - residual: transpose via LDS for coalesced writes
    float* Rf = (float*)lds;
    __syncthreads();
#define TW(i) *reinterpret_cast<float4*>(Rf + row * DN + KS + (i) * 4) = rr##i;
    TW(0) TW(1) TW(2) TW(3) TW(4) TW(5) TW(6) TW(7)
    TW(8) TW(9) TW(10) TW(11) TW(12) TW(13) TW(14) TW(15)
#undef TW
    __syncthreads();
    {
        const int row2 = t >> 2;
        const int kb2  = (t & 3) * 64;
        const float* ir = in + (size_t)(base + row2) * DN + kb2;
        float* orp = out + (size_t)(base + row2) * DN + kb2;
        const float* rf = Rf + row2 * DN + kb2;
#pragma unroll
        for (int i = 0; i < 16; ++i) {
            const float4 rv = *reinterpret_cast<const float4*>(rf + i * 4);
            const float4 iv = *reinterpret_cast<const float4*>(ir + i * 4);
            float4 ov;
            ov.x = iv.x - rv.x; ov.y = iv.y - rv.y;
            ov.z = iv.z - rv.z; ov.w = iv.w - rv.w;
            *reinterpret_cast<float4*>(orp + i * 4) = ov;
        }
    }
}

extern "C" void kernel_launch(void* const* d_in, const int* in_sizes, int n_in,
                              void* d_out, int out_size, void* d_ws, size_t ws_size,
                              hipStream_t stream) {
    (void)in_sizes; (void)n_in; (void)out_size; (void)ws_size;
    const float* in = (const float*)d_in[0];
    const float* cb = (const float*)d_in[1];
    float* out = (float*)d_out;
    u16* bhp = (u16*)d_ws;                          // 4.19 MB hi plane
    u16* bmp = bhp + (size_t)QN * CN * DN;          // 4.19 MB mid plane
    float* invw = (float*)(bmp + (size_t)QN * CN * DN);  // 32 KB inv table

    rvq_prep<<<dim3(2048), dim3(256), 0, stream>>>(cb, bhp, bmp, invw, out);
    rvq_main<<<dim3(512), dim3(256), 0, stream>>>(in, cb, bhp, bmp, invw, out);
}